// Round 6
// baseline (3132.923 us; speedup 1.0000x reference)
//
#include <hip/hip_runtime.h>
#include <hip/hip_bf16.h>

// ---------------------------------------------------------------------------
// PoseFeatureNet R6:
//  - k_lstm_f5: paired-WG column-split recurrence. 16 WGs = 8 pairs x 2
//    halves; each WG owns 512 of 1024 gate-cols -> Whh slice (256 KB) FULLY
//    VGPR-resident (64 VGPR/wave x 16 waves). Waves split K (kc0-3/kc4-7),
//    partials summed via LDS. Halves exchange h (hi+lo bf16, 8 KB) per step
//    via global + release/acquire counter flags; ks1 waves spin+read while
//    ks0 waves do gates. Zero per-step Whh streaming.
//  - k_wfrag/k_gemm_mfma epilogue repacked for this layout.
//  - k_gcnfused / k_lstm_b / k_head unchanged.
// ---------------------------------------------------------------------------

#define TT 256
#define BB 128
#define NNODE 17
#define DD 2176    // 17*128
#define LHID 256
#define G4 1024    // 4*LHID
#define NCLS 625

typedef unsigned short u16t;

__device__ __constant__ int ESRC[19] = {15,13,16,14,11,5,6,5,5,6,7,8,1,0,0,1,2,3,4};
__device__ __constant__ int EDST[19] = {13,11,14,12,12,11,12,6,7,8,9,10,2,1,2,3,4,5,6};
__device__ __constant__ float DEGF[17] = {1,2,3,2,2,2,3,2,2,2,2,3,4,2,2,1,1};

__device__ inline float lo2f(unsigned u){ union{unsigned x; float f;} c; c.x = u << 16; return c.f; }
__device__ inline float hi2f(unsigned u){ union{unsigned x; float f;} c; c.x = u & 0xffff0000u; return c.f; }
__device__ inline u16t f2b(float f){
    __hip_bfloat16 h = __float2bfloat16(f);
    u16t s; __builtin_memcpy(&s, &h, 2); return s;
}
__device__ inline float b2f(u16t s){ union{unsigned x; float f;} c; c.x = ((unsigned)s) << 16; return c.f; }
__device__ inline unsigned pack2(float a, float b){
    return (unsigned)f2b(a) | ((unsigned)f2b(b) << 16);
}
__device__ inline float fsig(float x){ return __fdividef(1.f, 1.f + __expf(-x)); }
__device__ inline float ftanh(float x){ float e = __expf(2.f*x); return 1.f - __fdividef(2.f, e + 1.f); }
__device__ inline float sigm(float x){ return 1.f / (1.f + expf(-x)); }

typedef __attribute__((ext_vector_type(8))) short bf16x8;
typedef __attribute__((ext_vector_type(4))) float f32x4;

__device__ inline void gload16(const void* g, void* l){
    __builtin_amdgcn_global_load_lds(
        (const __attribute__((address_space(1))) void*)g,
        (__attribute__((address_space(3))) void*)l, 16, 0, 0);
}

// ----------------------------------------------------------- zero sync flags
__global__ void k_zeroflags(int* __restrict__ flags){
    flags[threadIdx.x] = 0;   // 256 ints = 1 KB
}

// --------------------------------------------- W2 -> bf16 transposed [n][k]
__global__ void k_w2t(const float* __restrict__ W2, __hip_bfloat16* __restrict__ W2Tb){
    int g = blockIdx.x * 256 + threadIdx.x;   // 16384
    int k = g >> 7, n = g & 127;
    W2Tb[n * 128 + k] = __float2bfloat16(W2[g]);
}

// ------------------- Whh -> bf16 fragments, R6 packing
// f = (((hf*2 + ks)*8 + jt)*4 + kc4)*4 + gate   (512 frags x 64 lanes x 16B)
// lane l: B[k = (ks*4+kc4)*32 + (l>>4)*8 ..+8][col = gate*256 + hf*128 + jt*16 + (l&15)]
__global__ void k_wfrag(const float* __restrict__ Whh, __hip_bfloat16* __restrict__ WTfrag){
    int g = blockIdx.x * 256 + threadIdx.x;   // 32768
    int f = g >> 6, lane = g & 63;
    int gate = f & 3, kc4 = (f >> 2) & 3, jt = (f >> 4) & 7, ks = (f >> 7) & 1, hf = (f >> 8) & 1;
    int col = gate*256 + hf*128 + jt*16 + (lane & 15);
    int k0  = (ks*4 + kc4)*32 + (lane >> 4)*8;
    const float* src = Whh + (size_t)col * 256 + k0;
    float4 f0 = *(const float4*)src;
    float4 f1 = *(const float4*)(src + 4);
    uint4 o;
    o.x = pack2(f0.x, f0.y); o.y = pack2(f0.z, f0.w);
    o.z = pack2(f1.x, f1.y); o.w = pack2(f1.z, f1.w);
    *(uint4*)((char*)WTfrag + (size_t)g * 16) = o;
}

// ------------------------------------------------------------ fused GCN block
__global__ __launch_bounds__(512) void k_gcnfused(
    const float* __restrict__ pose1, const float* __restrict__ pose2,
    const float* __restrict__ W1, const float* __restrict__ b1,
    const float* __restrict__ b2, const __hip_bfloat16* __restrict__ W2Tb,
    __hip_bfloat16* __restrict__ feats)
{
    __shared__ u16t  Abuf[272][136];
    __shared__ u16t  BsmT[128][136];
    __shared__ float ps4[2][16][17][4];
    __shared__ float araw[17*128];
    __shared__ float araw2[17*128];
    __shared__ float As[289];

    const int tid = threadIdx.x;
    const int blk = blockIdx.x;
    const int t   = blk >> 3;
    const int bc  = blk & 7;

    for (int idx = tid; idx < 1632; idx += 512){
        int p_ = idx >= 816 ? 1 : 0;
        int r  = idx - p_ * 816;
        int bl = r / 51, i = r - bl * 51;
        int n = i / 3, c = i - n * 3;
        const float* src = p_ ? pose2 : pose1;
        ps4[p_][bl][n][c] = src[(size_t)((bc*16 + bl) * TT + t) * 51 + i];
    }
    {
        const uint4* src = (const uint4*)W2Tb;
        for (int r = 0; r < 2; ++r){
            int f0 = (tid + r * 512) * 16;
            int n = f0 >> 7, k0 = f0 & 127;
            uint4 v0 = src[(tid + r*512)*2 + 0];
            uint4 v1 = src[(tid + r*512)*2 + 1];
            *(uint4*)&BsmT[n][k0]     = v0;
            *(uint4*)&BsmT[n][k0 + 8] = v1;
        }
    }
    if (bc == 0 && tid < 289){
        int i = tid / 17, j = tid - (tid/17)*17;
        float a = (i == j) ? 1.0f / DEGF[i] : 0.0f;
        for (int e = 0; e < 19; ++e)
            if (EDST[e] == i && ESRC[e] == j)
                a += 1.0f / sqrtf(DEGF[i] * DEGF[j]);
        As[tid] = a;
    }

    const int h = tid & 127;
    const int q = tid >> 7;
    const float w10 = W1[h], w11 = W1[128 + h], w12 = W1[256 + h];
    const float b1h = b1[h];
    __syncthreads();

    float a2st[5];
    int nl[5], nv = 0;
    for (int s = 0; s < 5; ++s){ int n = q + 4*s; if (n < NNODE) nl[nv++] = n; }
    for (int s = 0; s < nv; ++s){
        int n = nl[s];
        for (int bl = 0; bl < 16; ++bl){
            float4 p1 = *(const float4*)&ps4[0][bl][n][0];
            float4 p2 = *(const float4*)&ps4[1][bl][n][0];
            float a1 = p1.x*w10 + p1.y*w11 + p1.z*w12;
            float a2 = p2.x*w10 + p2.y*w11 + p2.z*w12;
            if (bc == 0 && bl == 0){
                araw[n*128 + h] = a1;
                a2st[s] = a2;
            } else {
                float r1 = fmaxf(a1 + b1h, 0.f);
                float r2 = fmaxf(a2 + b1h, 0.f);
                Abuf[n*16 + bl][h] = f2b(0.5f*(r1 + r2));
            }
        }
    }
    __syncthreads();
    if (bc == 0){
        for (int s = 0; s < nv; ++s){
            int n = nl[s]; float a = 0.f;
            #pragma unroll
            for (int j = 0; j < NNODE; ++j) a += As[n*17 + j] * araw[j*128 + h];
            araw2[n*128 + h] = fmaxf(a + b1h, 0.f);
        }
    }
    __syncthreads();
    if (bc == 0){
        for (int s = 0; s < nv; ++s){
            int n = nl[s]; float a = 0.f;
            #pragma unroll
            for (int j = 0; j < NNODE; ++j) a += As[n*17 + j] * araw2[j*128 + h];
            float r2 = fmaxf(a2st[s] + b1h, 0.f);
            Abuf[n*16 + 0][h] = f2b(0.5f*(a + r2));
        }
    }
    __syncthreads();

    const int w = tid >> 6, l = tid & 63;
    const int l15 = l & 15, q8 = (l >> 4) * 8, q4 = (l >> 4) * 4;
    float bias[8];
    #pragma unroll
    for (int nt = 0; nt < 8; ++nt) bias[nt] = b2[nt*16 + l15];

    bf16x8 Bf[4][8];
    #pragma unroll
    for (int kc = 0; kc < 4; ++kc)
        #pragma unroll
        for (int nt = 0; nt < 8; ++nt)
            Bf[kc][nt] = *(const bf16x8*)&BsmT[nt*16 + l15][kc*32 + q8];

    u16t* Cb = (u16t*)feats;
    for (int mt = w; mt < NNODE; mt += 8){
        f32x4 acc[8];
        #pragma unroll
        for (int nt = 0; nt < 8; ++nt) acc[nt] = (f32x4){0.f,0.f,0.f,0.f};
        #pragma unroll
        for (int kc = 0; kc < 4; ++kc){
            bf16x8 a = *(const bf16x8*)&Abuf[mt*16 + l15][kc*32 + q8];
            #pragma unroll
            for (int nt = 0; nt < 8; ++nt)
                acc[nt] = __builtin_amdgcn_mfma_f32_16x16x32_bf16(a, Bf[kc][nt], acc[nt], 0,0,0);
        }
        #pragma unroll
        for (int nt = 0; nt < 8; ++nt)
            #pragma unroll
            for (int r = 0; r < 4; ++r){
                size_t row = (size_t)(blk*16 + q4 + r) * NNODE + mt;
                Cb[row*128 + nt*16 + l15] = f2b(acc[nt][r] + bias[nt]);
            }
    }
}

// ------------------------------------------------- pre_f GEMM: bf16 MFMA
// R6 epilogue: col = gate*256 + jg, jg = hf*128 + jl, jl = jt*16 + l15;
// b: p=b>>4, q=(b&15)>>2, r=b&3
// off = t*131072 + p*16384 + hf*8192 + jt*1024 + q*256 + r*64 + l15*4 + gate
__global__ __launch_bounds__(256) void k_gemm_mfma(
    const __hip_bfloat16* __restrict__ A, const float* __restrict__ Bw,
    const float* __restrict__ bi1, const float* __restrict__ bi2,
    u16t* __restrict__ pre2)
{
    __shared__ u16t Asm[128][32];
    __shared__ u16t Bsm[128][32];
    const int tid = threadIdx.x;
    const int w = tid >> 6;
    const int l = tid & 63;
    const size_t m0 = (size_t)blockIdx.x * 128;
    const int n0 = blockIdx.y * 128;
    const int mw = (w >> 1) * 64;
    const int nw = (w & 1) * 64;

    f32x4 acc[4][4];
    #pragma unroll
    for (int s = 0; s < 4; ++s)
        #pragma unroll
        for (int t_ = 0; t_ < 4; ++t_)
            acc[s][t_] = (f32x4){0.f, 0.f, 0.f, 0.f};

    const u16t* Ab = (const u16t*)A;
    const int arow = w*32 + (l>>2);
    const int akoff = (l&3)*8;
    const int brow = w*32 + (l>>1);
    const int bko  = (l&1)*16;
    const int fr = l & 15, fq = (l >> 4) * 8;

    for (int kt = 0; kt < DD; kt += 32){
        gload16(Ab + (m0 + arow)*DD + kt + akoff,      &Asm[arow][akoff]);
        gload16(Ab + (m0 + arow + 16)*DD + kt + akoff, &Asm[arow+16][akoff]);
        const float* bp = Bw + (size_t)(n0 + brow)*DD + kt + bko;
        float4 f0 = *(const float4*)bp;
        float4 f1 = *(const float4*)(bp+4);
        float4 f2 = *(const float4*)(bp+8);
        float4 f3 = *(const float4*)(bp+12);
        uint4 o0, o1;
        o0.x = pack2(f0.x,f0.y); o0.y = pack2(f0.z,f0.w);
        o0.z = pack2(f1.x,f1.y); o0.w = pack2(f1.z,f1.w);
        o1.x = pack2(f2.x,f2.y); o1.y = pack2(f2.z,f2.w);
        o1.z = pack2(f3.x,f3.y); o1.w = pack2(f3.z,f3.w);
        *(uint4*)&Bsm[brow][bko]   = o0;
        *(uint4*)&Bsm[brow][bko+8] = o1;
        __syncthreads();

        bf16x8 af[4], bf[4];
        #pragma unroll
        for (int s = 0; s < 4; ++s) af[s] = *(const bf16x8*)&Asm[mw + s*16 + fr][fq];
        #pragma unroll
        for (int t_ = 0; t_ < 4; ++t_) bf[t_] = *(const bf16x8*)&Bsm[nw + t_*16 + fr][fq];
        #pragma unroll
        for (int s = 0; s < 4; ++s)
            #pragma unroll
            for (int t_ = 0; t_ < 4; ++t_)
                acc[s][t_] = __builtin_amdgcn_mfma_f32_16x16x32_bf16(af[s], bf[t_], acc[s][t_], 0, 0, 0);
        __syncthreads();
    }

    const int cr = (l >> 4) * 4;
    const int cc = l & 15;
    const int tIdx = blockIdx.x;
    #pragma unroll
    for (int t_ = 0; t_ < 4; ++t_){
        int col = n0 + nw + t_*16 + cc;
        float bias = bi1[col] + bi2[col];
        int gate = col >> 8;
        int jg   = col & 255;
        size_t cbase = (size_t)tIdx*131072 + (size_t)(jg >> 7)*8192
                     + (size_t)((jg & 127) >> 4)*1024 + (size_t)(jg & 15)*4 + gate;
        #pragma unroll
        for (int s = 0; s < 4; ++s)
            #pragma unroll
            for (int r = 0; r < 4; ++r){
                int b = mw + s*16 + cr + r;
                pre2[cbase + (size_t)(b>>4)*16384 + ((b&15)>>2)*256 + (b&3)*64]
                    = f2b(acc[s][t_][r] + bias);
            }
    }
}

// --------------------- backward LSTM: one step from zero state (unchanged)
__global__ __launch_bounds__(256) void k_lstm_b(
    const __hip_bfloat16* __restrict__ feats255,
    const float* __restrict__ Wih_b,
    const float* __restrict__ bih_b, const float* __restrict__ bhh_b,
    float* __restrict__ h_b)
{
    __shared__ float fs[DD];
    const int tid = threadIdx.x;
    const int b = blockIdx.x;
    const unsigned* fbu = (const unsigned*)(feats255 + (size_t)b * DD);
    for (int i = tid; i < DD/2; i += 256){
        unsigned u = fbu[i];
        fs[2*i] = lo2f(u); fs[2*i+1] = hi2f(u);
    }
    __syncthreads();

    const int w = tid >> 6, lane = tid & 63;
    const int j = blockIdx.y * 4 + w;
    const float* Wi = Wih_b + (size_t)j * DD;
    const float* Wg = Wih_b + (size_t)(512 + j) * DD;
    const float* Wo = Wih_b + (size_t)(768 + j) * DD;
    float si = 0.f, sg = 0.f, so = 0.f;
    #pragma unroll 2
    for (int i = 0; i < 34; ++i){
        int k = lane + i*64;
        float f = fs[k];
        si += f * Wi[k]; sg += f * Wg[k]; so += f * Wo[k];
    }
    #pragma unroll
    for (int off = 32; off > 0; off >>= 1){
        si += __shfl_down(si, off);
        sg += __shfl_down(sg, off);
        so += __shfl_down(so, off);
    }
    if (lane == 0){
        float zi = si + bih_b[j]       + bhh_b[j];
        float zg = sg + bih_b[512 + j] + bhh_b[512 + j];
        float zo = so + bih_b[768 + j] + bhh_b[768 + j];
        float c = sigm(zi) * tanhf(zg);
        h_b[(size_t)b*LHID + j] = sigm(zo) * tanhf(c);
    }
}

// ------------------- forward LSTM R6: paired-WG col split, Whh VGPR-resident
// grid 16 (pair p = blk>>1, half hf = blk&1), 1024 threads.
// wave w: ks = w>>3 (K half), jt = w&7 (j-tile in my 128-col half).
// ks0 waves: gates + own-h publish; ks1 waves: z-partials + partner-h import.
__global__ __launch_bounds__(1024, 4) void k_lstm_f5(
    const u16t* __restrict__ pre2,
    const __hip_bfloat16* __restrict__ WTfrag,
    u16t* __restrict__ hx,        // [pair][hf][slot2][plane2][s16][j128] u16
    int* __restrict__ flags,      // [pair*2+hf]*16 ints (64B apart)
    float* __restrict__ hout)     // (128,256) fp32
{
    __shared__ u16t hAhi[16][264];
    __shared__ u16t hAlo[16][264];
    __shared__ float zbuf[4][16][132];

    const int tid = threadIdx.x;
    const int blk = blockIdx.x;
    const int p = blk >> 1, hf = blk & 1;
    const int w = tid >> 6, l = tid & 63;
    const int ks = w >> 3, jt = w & 7;
    const int q = l >> 4, l15 = l & 15, q8 = q*8;
    const u16t* wtf = (const u16t*)WTfrag;

    for (int i = tid; i < 16*264; i += 1024){
        ((u16t*)hAhi)[i] = 0; ((u16t*)hAlo)[i] = 0;
    }

    // resident Whh fragments: 16 frags = 64 VGPRs
    bf16x8 Bres[4][4];
    #pragma unroll
    for (int kc4 = 0; kc4 < 4; ++kc4)
        #pragma unroll
        for (int gt = 0; gt < 4; ++gt){
            size_t f = ((((size_t)hf*2 + ks)*8 + jt)*4 + kc4)*4 + gt;
            Bres[kc4][gt] = *(const bf16x8*)(wtf + (f*64 + l)*8);
        }

    float cst[4] = {0.f, 0.f, 0.f, 0.f};
    const size_t pbase = (size_t)p*16384 + (size_t)hf*8192 + (size_t)jt*1024
                       + (size_t)q*256 + (size_t)l15*4;
    u16t*       hx_my = hx + ((size_t)(p*2 + hf))    * 8192;
    const u16t* hx_pt = hx + ((size_t)(p*2 + (hf^1)))* 8192;
    int* flag_my = flags + (p*2 + hf)*16;
    int* flag_pt = flags + (p*2 + (hf^1))*16;
    const int jl = jt*16 + l15;
    const int jg = hf*128 + jl;

    __syncthreads();

    #pragma unroll 1
    for (int t = 0; t < TT; ++t){
        union { uint2 v; u16t s[4]; } pr[4];
        if (ks == 0){
            const u16t* pp = pre2 + (size_t)t*131072 + pbase;
            #pragma unroll
            for (int r = 0; r < 4; ++r) pr[r].v = *(const uint2*)(pp + r*64);
        }

        f32x4 acc[4];
        #pragma unroll
        for (int gt = 0; gt < 4; ++gt) acc[gt] = (f32x4){0.f,0.f,0.f,0.f};
        #pragma unroll
        for (int kc4 = 0; kc4 < 4; ++kc4){
            const int kca = ks*4 + kc4;
            bf16x8 ah = *(const bf16x8*)&hAhi[l15][kca*32 + q8];
            bf16x8 al = *(const bf16x8*)&hAlo[l15][kca*32 + q8];
            #pragma unroll
            for (int gt = 0; gt < 4; ++gt)
                acc[gt] = __builtin_amdgcn_mfma_f32_16x16x32_bf16(ah, Bres[kc4][gt], acc[gt], 0,0,0);
            #pragma unroll
            for (int gt = 0; gt < 4; ++gt)
                acc[gt] = __builtin_amdgcn_mfma_f32_16x16x32_bf16(al, Bres[kc4][gt], acc[gt], 0,0,0);
        }
        if (ks == 1){
            #pragma unroll
            for (int gt = 0; gt < 4; ++gt)
                #pragma unroll
                for (int r = 0; r < 4; ++r)
                    zbuf[gt][q*4 + r][jl] = acc[gt][r];
        }
        __syncthreads();   // B1: z-partials visible, all MFMA reads of hA done

        const int slot = t & 1;
        if (ks == 0){
            u16t* hw = hx_my + slot*4096;
            #pragma unroll
            for (int r = 0; r < 4; ++r){
                const int s = q*4 + r;
                float zi = acc[0][r] + zbuf[0][s][jl] + b2f(pr[r].s[0]);
                float zf = acc[1][r] + zbuf[1][s][jl] + b2f(pr[r].s[1]);
                float zg = acc[2][r] + zbuf[2][s][jl] + b2f(pr[r].s[2]);
                float zo = acc[3][r] + zbuf[3][s][jl] + b2f(pr[r].s[3]);
                float cn = fsig(zf)*cst[r] + fsig(zi)*ftanh(zg);
                cst[r] = cn;
                float hh = fsig(zo)*ftanh(cn);
                u16t hb = f2b(hh);
                u16t lb = f2b(hh - b2f(hb));
                hAhi[s][jg] = hb;
                hAlo[s][jg] = lb;
                hw[s*128 + jl]        = hb;   // plane 0: hi, [s][j]
                hw[2048 + s*128 + jl] = lb;   // plane 1: lo
                if (t == TT-1)
                    hout[((size_t)p*16 + s)*LHID + jg] = hh;
            }
            if (l == 0)
                __hip_atomic_fetch_add(flag_my, 1, __ATOMIC_RELEASE, __HIP_MEMORY_SCOPE_AGENT);
        } else {
            const int thr = 8*(t + 1);
            while (__hip_atomic_load(flag_pt, __ATOMIC_ACQUIRE, __HIP_MEMORY_SCOPE_AGENT) < thr)
                __builtin_amdgcn_s_sleep(1);
            const int rid = (w - 8)*64 + l;     // 0..511
            uint4 v = *(const uint4*)(hx_pt + slot*4096 + rid*8);
            const int plane = rid >> 8;
            const int s = (rid >> 4) & 15;
            const int j8 = (rid & 15)*8;
            u16t* dst = plane ? &hAlo[s][(hf^1)*128 + j8] : &hAhi[s][(hf^1)*128 + j8];
            *(uint4*)dst = v;
        }
        __syncthreads();   // B2: hA(t+1) complete
    }
}

// ----------------------------------------------------- head (unchanged)
__global__ __launch_bounds__(256) void k_head(
    const float* __restrict__ h_f, const float* __restrict__ h_b,
    const float* __restrict__ Wc, const float* __restrict__ bc,
    float* __restrict__ out)
{
    __shared__ float pool[512];
    const int b = blockIdx.x, tid = threadIdx.x;
    float p0 = fmaxf(h_f[(size_t)b*LHID + tid], 0.f);
    float p1 = fmaxf(h_b[(size_t)b*LHID + tid], 0.f);
    pool[tid] = p0; pool[256 + tid] = p1;
    out[(size_t)b*512 + tid]       = p0;
    out[(size_t)b*512 + 256 + tid] = p1;
    __syncthreads();
    for (int n = tid; n < NCLS; n += 256){
        float a = bc[n];
        const float* ww = Wc + (size_t)n * 512;
        #pragma unroll 4
        for (int k = 0; k < 512; k += 4){
            float4 wv = *(const float4*)(ww + k);
            a += pool[k]*wv.x + pool[k+1]*wv.y + pool[k+2]*wv.z + pool[k+3]*wv.w;
        }
        out[(size_t)BB*512 + (size_t)b*NCLS + n] = a;
    }
}

// ---------------------------------------------------------------------------
extern "C" void kernel_launch(void* const* d_in, const int* in_sizes, int n_in,
                              void* d_out, int out_size, void* d_ws, size_t ws_size,
                              hipStream_t stream) {
    const float* pose1 = (const float*)d_in[0];
    const float* pose2 = (const float*)d_in[1];
    const float* W1    = (const float*)d_in[2];
    const float* b1    = (const float*)d_in[3];
    const float* W2    = (const float*)d_in[4];
    const float* b2    = (const float*)d_in[5];
    const float* Wih_f = (const float*)d_in[6];
    const float* Whh_f = (const float*)d_in[7];
    const float* bih_f = (const float*)d_in[8];
    const float* bhh_f = (const float*)d_in[9];
    const float* Wih_b = (const float*)d_in[10];
    const float* bih_b = (const float*)d_in[12];
    const float* bhh_b = (const float*)d_in[13];
    const float* Wc    = (const float*)d_in[14];
    const float* bc    = (const float*)d_in[15];
    (void)in_sizes; (void)n_in; (void)out_size; (void)ws_size;
    float* out = (float*)d_out;
    char* ws = (char*)d_ws;

    // workspace (within the 211,812,352-byte footprint used since R1)
    __hip_bfloat16* WTfrag = (__hip_bfloat16*)(ws + 0);           // 524,288
    __hip_bfloat16* W2Tb   = (__hip_bfloat16*)(ws + 524288);      //  32,768
    int*            flags  = (int*)(ws + 557056);                 //   1,024
    u16t*           hx     = (u16t*)(ws + 589824);                // 262,144
    float*          h_b    = (float*)(ws + 851968);               // 131,072
    float*          h_f    = (float*)(ws + 983040);               // 131,072
    __hip_bfloat16* feats  = (__hip_bfloat16*)(ws + 2097152);     // 142,606,336
    u16t*           pre2   = (u16t*)(ws + 144703488);             //  67,108,864

    k_zeroflags<<<1, 256, 0, stream>>>(flags);
    k_w2t     <<<64, 256, 0, stream>>>(W2, W2Tb);
    k_wfrag   <<<128, 256, 0, stream>>>(Whh_f, WTfrag);
    k_gcnfused<<<2048, 512, 0, stream>>>(pose1, pose2, W1, b1, b2, W2Tb, feats);
    k_gemm_mfma<<<dim3(256, 8), 256, 0, stream>>>(feats, Wih_f, bih_f, bhh_f, pre2);
    k_lstm_b  <<<dim3(128, 64), 256, 0, stream>>>(feats + (size_t)255*BB*DD, Wih_b, bih_b, bhh_b, h_b);
    k_lstm_f5 <<<16, 1024, 0, stream>>>(pre2, WTfrag, hx, flags, h_f);
    k_head    <<<128, 256, 0, stream>>>(h_f, h_b, Wc, bc, out);
}